// Round 1
// 12614.732 us; speedup vs baseline: 1.2507x; 1.2507x over previous
//
#include <hip/hip_runtime.h>
#include <math.h>

#define T_LEN 512
#define B_SZ  32
#define I_DIM 512
#define H_DIM 1024
#define NBLK  256
#define HS    (B_SZ * H_DIM)   // 32768 floats per state snapshot

typedef float fx4 __attribute__((ext_vector_type(4)));   // nontemporal-compatible

// ---------------------------------------------------------------------------
// bias_combine
// ---------------------------------------------------------------------------
__global__ void bias_combine(const float* __restrict__ b_ii, const float* __restrict__ b_hi,
                             const float* __restrict__ b_ci, const float* __restrict__ b_if,
                             const float* __restrict__ b_hf, const float* __restrict__ b_cf,
                             const float* __restrict__ b_ic, const float* __restrict__ b_hc,
                             const float* __restrict__ b_io, const float* __restrict__ b_ho,
                             const float* __restrict__ b_cyo, float* __restrict__ bias4) {
    int r = blockIdx.x * 256 + threadIdx.x;
    if (r < H_DIM) {
        bias4[r]        = b_ii[r] + b_hi[r] + b_ci[r];
        bias4[1024 + r] = b_if[r] + b_hf[r] + b_cf[r];
        bias4[2048 + r] = b_ic[r] + b_hc[r];
        bias4[3072 + r] = b_io[r] + b_ho[r] + b_cyo[r];
    }
}

// ---------------------------------------------------------------------------
// pregemm: C[n][m] = sum_k A[m][k]*W[nloc][k] + bias4[n]   (TRANSPOSED output:
// leading dim M, so the scan's per-step reads are coalesced over m.)
// M = Tc*32, K = 512, N = 4096. 128x128 tile, BK=16, 256 thr, 8x8/thread.
// ---------------------------------------------------------------------------
#define BM 128
#define BN 128
#define BK 16
__global__ __launch_bounds__(256) void pregemm(const float* __restrict__ A,
                                               const float* __restrict__ w0,
                                               const float* __restrict__ w1,
                                               const float* __restrict__ w2,
                                               const float* __restrict__ w3,
                                               const float* __restrict__ bias4,
                                               float* __restrict__ C, int M) {
    __shared__ float As[BK][BM + 4];
    __shared__ float Bs[BK][BN + 4];
    int tid = threadIdx.x;
    int n0 = blockIdx.y * BN;
    const float* W = (n0 < 1024) ? w0 : (n0 < 2048) ? w1 : (n0 < 3072) ? w2 : w3;
    int nloc = n0 & 1023;

    int lr = tid >> 2;
    int lk = (tid & 3) << 2;
    const float* Arow = A + (size_t)(blockIdx.x * BM + lr) * I_DIM + lk;
    const float* Brow = W + (size_t)(nloc + lr) * I_DIM + lk;

    float acc[8][8];
#pragma unroll
    for (int i = 0; i < 8; ++i)
#pragma unroll
        for (int j = 0; j < 8; ++j) acc[i][j] = 0.f;

    int mth = (tid >> 4) << 3;
    int nth = (tid & 15) << 3;

    for (int kt = 0; kt < I_DIM; kt += BK) {
        float4 a0 = *(const float4*)(Arow + kt);
        float4 a1 = *(const float4*)(Arow + 64 * I_DIM + kt);
        float4 b0 = *(const float4*)(Brow + kt);
        float4 b1 = *(const float4*)(Brow + 64 * I_DIM + kt);
        __syncthreads();
        As[lk + 0][lr] = a0.x; As[lk + 1][lr] = a0.y; As[lk + 2][lr] = a0.z; As[lk + 3][lr] = a0.w;
        As[lk + 0][lr + 64] = a1.x; As[lk + 1][lr + 64] = a1.y; As[lk + 2][lr + 64] = a1.z; As[lk + 3][lr + 64] = a1.w;
        Bs[lk + 0][lr] = b0.x; Bs[lk + 1][lr] = b0.y; Bs[lk + 2][lr] = b0.z; Bs[lk + 3][lr] = b0.w;
        Bs[lk + 0][lr + 64] = b1.x; Bs[lk + 1][lr + 64] = b1.y; Bs[lk + 2][lr + 64] = b1.z; Bs[lk + 3][lr + 64] = b1.w;
        __syncthreads();
#pragma unroll
        for (int j = 0; j < BK; ++j) {
            float am[8], bn[8];
            *(float4*)&am[0] = *(const float4*)&As[j][mth];
            *(float4*)&am[4] = *(const float4*)&As[j][mth + 4];
            *(float4*)&bn[0] = *(const float4*)&Bs[j][nth];
            *(float4*)&bn[4] = *(const float4*)&Bs[j][nth + 4];
#pragma unroll
            for (int ii = 0; ii < 8; ++ii)
#pragma unroll
                for (int jj = 0; jj < 8; ++jj) acc[ii][jj] += am[ii] * bn[jj];
        }
    }

    int mbase = blockIdx.x * BM + mth;
#pragma unroll
    for (int jj = 0; jj < 8; ++jj) {
        int n = n0 + nth + jj;
        float bn = bias4[n];
        float* crow = C + (size_t)n * M + mbase;
        fx4 v0, v1;
        v0.x = acc[0][jj] + bn; v0.y = acc[1][jj] + bn;
        v0.z = acc[2][jj] + bn; v0.w = acc[3][jj] + bn;
        v1.x = acc[4][jj] + bn; v1.y = acc[5][jj] + bn;
        v1.z = acc[6][jj] + bn; v1.w = acc[7][jj] + bn;
        __builtin_nontemporal_store(v0, (fx4*)crow);
        __builtin_nontemporal_store(v1, (fx4*)(crow + 4));
    }
}

// ---------------------------------------------------------------------------
// helpers
// ---------------------------------------------------------------------------
__device__ __forceinline__ float sigm(float x) { return 1.f / (1.f + __expf(-x)); }
__device__ __forceinline__ float tanh_fast(float x) { return 2.f / (1.f + __expf(-2.f * x)) - 1.f; }

__device__ __forceinline__ void agent_store(float* p, float v) {
    __hip_atomic_store(p, v, __ATOMIC_RELAXED, __HIP_MEMORY_SCOPE_AGENT);
}

// two-level arrival barrier (thread 0 only); no cache-flush fences.
__device__ __forceinline__ void arrive_wait(unsigned* grp, unsigned* master,
                                            int grpid, unsigned bidx) {
    unsigned old = __hip_atomic_fetch_add(&grp[grpid * 16], 1u,
                                          __ATOMIC_RELAXED, __HIP_MEMORY_SCOPE_AGENT);
    if (old == bidx * 32u + 31u)
        __hip_atomic_fetch_add(master, 1u, __ATOMIC_RELAXED, __HIP_MEMORY_SCOPE_AGENT);
    while (__hip_atomic_load(master, __ATOMIC_RELAXED, __HIP_MEMORY_SCOPE_AGENT)
           < (bidx + 1u) * 8u)
        __builtin_amdgcn_s_sleep(1);
}

// ---------------------------------------------------------------------------
// Persistent cooperative scan. 256 blocks x 512 thr (8 waves); block owns
// rows r0..r0+3. ALL weights for those rows (112 KB) live in LDS, loaded once.
// Wave wv owns k-slice [wv*128, wv*128+128).
//
// Restructured pipeline (vs previous version):
//  * c-peephole dots (w_ci/w_cf @ c(t)) for step t+1 are computed inside
//    phase B(t), reusing the cy4 registers already loaded for the w_cyo dot.
//    Phase A therefore only does h-dots (1 global float4/iter instead of 2)
//    and the full c(t-1) global re-read is eliminated.
//  * cy_lds persists own-row c across steps -> finisher A no longer reloads
//    c_old from global with a 4KB-stride scatter.
//  * G loads for the current step's finisher are issued BEFORE the phase-A
//    k-loop (issue-early / consume-late), hiding HBM latency under FMAs.
//  * redB is a separate 4KB reduction buffer so phase-B's c-dot partials can
//    live in redA's gs1 slots across the barrier into step t+1.
// ---------------------------------------------------------------------------
#define SMEM_FLOATS (24576 + 4096 + 6144 + 1024 + 128 + 128)
#define SMEM_BYTES  (SMEM_FLOATS * 4)

__global__ __launch_bounds__(512) void lstm_scan(
    const float* __restrict__ G,
    const float* __restrict__ h0,
    const float* __restrict__ c_init,
    const float* __restrict__ w_hi, const float* __restrict__ w_ci,
    const float* __restrict__ w_hf, const float* __restrict__ w_cf,
    const float* __restrict__ w_hc, const float* __restrict__ w_ho,
    const float* __restrict__ w_cyo,
    float* __restrict__ out,
    float* __restrict__ c_hist,
    unsigned* __restrict__ grp_ctr,
    unsigned* __restrict__ master,
    int t0, int Tc, int M)
{
    extern __shared__ float smem[];
    float* wA     = smem;             // [6][4][1024]  96 KB
    float* wB     = wA + 24576;       // [4][1024]     16 KB
    float* redA   = wB + 4096;        // [8][24][32]   24 KB   (gate-slot partials)
    float* redB   = redA + 6144;      // [8][4][32]     4 KB   (cyo partials)
    float* po_lds = redB + 1024;      // [4][32]
    float* cy_lds = po_lds + 128;     // [4][32]  persistent own-row c state

    int tid = threadIdx.x;
    int blk = blockIdx.x;
    int r0 = blk * 4;
    int grpid = blk & 7;

    int wv = tid >> 6;            // 0..7 : k-split
    int lane = tid & 63;
    int half = lane >> 5;         // gate-row group
    int b = lane & 31;            // batch
    int kbase = wv * 128;

    // ---- load weight slices into LDS once ----
    {
        const float* srcs[7] = {w_hi, w_ci, w_hf, w_cf, w_hc, w_ho, w_cyo};
#pragma unroll
        for (int m = 0; m < 7; ++m) {
            const float4* s = (const float4*)(srcs[m] + (size_t)r0 * H_DIM);
            float4* d = (float4*)(m < 6 ? (wA + m * 4096) : wB);
            d[tid] = s[tid];
            d[tid + 512] = s[tid + 512];
        }
    }

    // slot gates: slot0/2 consume h, slot1 consumes c — uniform across halves.
    int gs0 = half ? 2 : 0;       // w_hf : w_hi   (h)
    int gs1 = half ? 3 : 1;       // w_cf : w_ci   (c)
    int gs2 = half ? 5 : 4;       // w_ho : w_hc   (h)

    // LDS weight pointers (kbase folded in, step-invariant)
    const float* wpk[12];
#pragma unroll
    for (int q = 0; q < 4; ++q) {
        wpk[q]     = wA + (gs0 * 4 + q) * 1024 + kbase;
        wpk[4 + q] = wA + (gs1 * 4 + q) * 1024 + kbase;
        wpk[8 + q] = wA + (gs2 * 4 + q) * 1024 + kbase;
    }
    const float* wBk0 = wB + (half * 2 + 0) * 1024 + kbase;
    const float* wBk1 = wB + (half * 2 + 1) * 1024 + kbase;

    // finisher mapping (threads 0..127)
    int frw = (tid >> 5) & 3;
    int fb = tid & 31;
    int fr = r0 + frw;

    __syncthreads();   // weights ready

    // ---- pre-loop: c-dots for step 0 from c_init + cy_lds init ----
    {
        const float* cb0 = c_init + (size_t)b * H_DIM + kbase;
        float ca[4];
#pragma unroll
        for (int q = 0; q < 4; ++q) ca[q] = 0.f;
#pragma unroll 8
        for (int it = 0; it < 32; ++it) {
            int k = it * 4;
            float4 c4 = *(const float4*)(cb0 + k);
#pragma unroll
            for (int q = 0; q < 4; ++q) {
                float4 w4 = *(const float4*)(wpk[4 + q] + k);
                ca[q] += w4.x * c4.x + w4.y * c4.y + w4.z * c4.z + w4.w * c4.w;
            }
        }
#pragma unroll
        for (int q = 0; q < 4; ++q)
            redA[wv * 768 + (gs1 * 4 + q) * 32 + b] = ca[q];
        if (tid < 128)
            cy_lds[frw * 32 + fb] = c_init[(size_t)fb * H_DIM + fr];
    }

    unsigned bidx = 0;

    for (int tt = 0; tt < Tc; ++tt) {
        int t = t0 + tt;
        const float* hp = (t == 0) ? h0 : out + (size_t)(t - 1) * HS;
        float* cw = c_hist + (size_t)(tt + 1) * HS;

        // ---------------- phase A main: h-dots only (8 partials) ----------------
        // G prefetch for this step's finisher: issue before the k-loop so the
        // HBM latency hides under ~1024 FMAs.
        float xi = 0.f, xf = 0.f, xg = 0.f, xo = 0.f;
        if (tid < 128) {
            int m = tt * 32 + fb;
            xi = __builtin_nontemporal_load(G + (size_t)(0 * 1024 + fr) * M + m);
            xf = __builtin_nontemporal_load(G + (size_t)(1 * 1024 + fr) * M + m);
            xg = __builtin_nontemporal_load(G + (size_t)(2 * 1024 + fr) * M + m);
            xo = __builtin_nontemporal_load(G + (size_t)(3 * 1024 + fr) * M + m);
        }

        const float* hb = hp + (size_t)b * H_DIM + kbase;
        float acc[8];
#pragma unroll
        for (int j = 0; j < 8; ++j) acc[j] = 0.f;

#pragma unroll 8
        for (int it = 0; it < 32; ++it) {
            int k = it * 4;
            float4 h4 = *(const float4*)(hb + k);
#pragma unroll
            for (int q = 0; q < 4; ++q) {
                float4 w4 = *(const float4*)(wpk[q] + k);
                acc[q] += w4.x * h4.x + w4.y * h4.y + w4.z * h4.z + w4.w * h4.w;
            }
#pragma unroll
            for (int q = 0; q < 4; ++q) {
                float4 w4 = *(const float4*)(wpk[8 + q] + k);
                acc[4 + q] += w4.x * h4.x + w4.y * h4.y + w4.z * h4.z + w4.w * h4.w;
            }
        }
#pragma unroll
        for (int q = 0; q < 4; ++q) {
            redA[wv * 768 + (gs0 * 4 + q) * 32 + b] = acc[q];
            redA[wv * 768 + (gs2 * 4 + q) * 32 + b] = acc[4 + q];
        }
        __syncthreads();

        // ---------------- phase A finisher (threads 0..127) ----------------
        // gs1 slots hold c-dot partials written by phase B(t-1) / pre-loop.
        if (tid < 128) {
            float s[6];
#pragma unroll
            for (int g = 0; g < 6; ++g) {
                float v = 0.f;
#pragma unroll
                for (int k8 = 0; k8 < 8; ++k8)
                    v += redA[k8 * 768 + (g * 4 + frw) * 32 + fb];
                s[g] = v;
            }
            float iv = sigm(xi + s[0] + s[1]);
            float fv = sigm(xf + s[2] + s[3]);
            float gv = tanh_fast(xg + s[4]);
            float cold = cy_lds[frw * 32 + fb];      // own c(t-1), persisted in LDS
            float cy = fv * cold + iv * gv;
            agent_store(&cw[(size_t)fb * H_DIM + fr], cy);
            po_lds[frw * 32 + fb] = xo + s[5];
            cy_lds[frw * 32 + fb] = cy;
        }
        __syncthreads();              // drains the agent stores too

        // ---------------- barrier: cy globally visible ----------------
        if (tid == 0) arrive_wait(grp_ctr, master, grpid, bidx);
        bidx++;
        __builtin_amdgcn_fence(__ATOMIC_ACQUIRE, "workgroup");
        __syncthreads();

        // ---------------- phase B main: o-gate peephole dot + next-step c-dots --
        // cy4 is loaded once and feeds BOTH the w_cyo dot (this step) and the
        // w_ci/w_cf dots (next step) -> the c-dots cost zero extra loads.
        const float* cyb = cw + (size_t)b * H_DIM + kbase;
        float a0 = 0.f, a1 = 0.f;
        float ca[4];
#pragma unroll
        for (int q = 0; q < 4; ++q) ca[q] = 0.f;
#pragma unroll 8
        for (int it = 0; it < 32; ++it) {
            int k = it * 4;
            float4 cy4 = *(const float4*)(cyb + k);
            float4 w0 = *(const float4*)(wBk0 + k);
            float4 w1 = *(const float4*)(wBk1 + k);
            a0 += w0.x * cy4.x + w0.y * cy4.y + w0.z * cy4.z + w0.w * cy4.w;
            a1 += w1.x * cy4.x + w1.y * cy4.y + w1.z * cy4.z + w1.w * cy4.w;
#pragma unroll
            for (int q = 0; q < 4; ++q) {
                float4 w4 = *(const float4*)(wpk[4 + q] + k);
                ca[q] += w4.x * cy4.x + w4.y * cy4.y + w4.z * cy4.z + w4.w * cy4.w;
            }
        }
        redB[wv * 128 + (half * 2 + 0) * 32 + b] = a0;
        redB[wv * 128 + (half * 2 + 1) * 32 + b] = a1;
#pragma unroll
        for (int q = 0; q < 4; ++q)
            redA[wv * 768 + (gs1 * 4 + q) * 32 + b] = ca[q];   // for step t+1
        __syncthreads();

        // ---------------- phase B finisher ----------------
        if (tid < 128) {
            float v = 0.f;
#pragma unroll
            for (int k8 = 0; k8 < 8; ++k8)
                v += redB[k8 * 128 + frw * 32 + fb];
            float o = sigm(po_lds[frw * 32 + fb] + v);
            float hy = o * tanh_fast(cy_lds[frw * 32 + fb]);
            agent_store(&out[(size_t)t * HS + (size_t)fb * H_DIM + fr], hy);
        }
        __syncthreads();

        // ---------------- barrier: h(t) globally visible ----------------
        if (tid == 0) arrive_wait(grp_ctr, master, grpid, bidx);
        bidx++;
        __builtin_amdgcn_fence(__ATOMIC_ACQUIRE, "workgroup");
        __syncthreads();
    }
}

// ---------------------------------------------------------------------------
extern "C" void kernel_launch(void* const* d_in, const int* in_sizes, int n_in,
                              void* d_out, int out_size, void* d_ws, size_t ws_size,
                              hipStream_t stream) {
    const float* X     = (const float*)d_in[0];
    const float* h0    = (const float*)d_in[1];
    const float* c0    = (const float*)d_in[2];
    const float* w_ii  = (const float*)d_in[3];
    const float* w_hi  = (const float*)d_in[4];
    const float* w_ci  = (const float*)d_in[5];
    const float* w_if  = (const float*)d_in[6];
    const float* w_hf  = (const float*)d_in[7];
    const float* w_cf  = (const float*)d_in[8];
    const float* w_ic  = (const float*)d_in[9];
    const float* w_hc  = (const float*)d_in[10];
    const float* w_io  = (const float*)d_in[11];
    const float* w_ho  = (const float*)d_in[12];
    const float* w_cyo = (const float*)d_in[13];
    const float* b_ii  = (const float*)d_in[14];
    const float* b_hi  = (const float*)d_in[15];
    const float* b_ci  = (const float*)d_in[16];
    const float* b_if  = (const float*)d_in[17];
    const float* b_hf  = (const float*)d_in[18];
    const float* b_cf  = (const float*)d_in[19];
    const float* b_ic  = (const float*)d_in[20];
    const float* b_hc  = (const float*)d_in[21];
    const float* b_io  = (const float*)d_in[22];
    const float* b_ho  = (const float*)d_in[23];
    const float* b_cyo = (const float*)d_in[24];
    float* out = (float*)d_out;

    (void)hipFuncSetAttribute((const void*)lstm_scan,
                              hipFuncAttributeMaxDynamicSharedMemorySize, SMEM_BYTES);

    // ws carve: G (4096 x M floats) | bias4 | c_hist ((Tc+1)*HS) | counters
    int Tc = 512;
    while (Tc > 8) {
        size_t need = ((size_t)Tc * 131072 + 4096 + (size_t)(Tc + 1) * HS) * 4 + 2048;
        if (need <= ws_size) break;
        Tc >>= 1;
    }
    int M = Tc * 32;

    float* G      = (float*)d_ws;
    float* bias4  = G + (size_t)Tc * 131072;
    float* c_hist = bias4 + 4096;
    unsigned* grp_ctr = (unsigned*)(c_hist + (size_t)(Tc + 1) * HS);
    unsigned* master  = grp_ctr + 256;

    bias_combine<<<4, 256, 0, stream>>>(b_ii, b_hi, b_ci, b_if, b_hf, b_cf,
                                        b_ic, b_hc, b_io, b_ho, b_cyo, bias4);

    const float* c_init = c0;
    for (int t0 = 0; t0 < T_LEN; t0 += Tc) {
        pregemm<<<dim3(M / BM, 4096 / BN), 256, 0, stream>>>(
            X + (size_t)t0 * B_SZ * I_DIM, w_ii, w_if, w_ic, w_io, bias4, G, M);
        (void)hipMemsetAsync(grp_ctr, 0, 2048, stream);

        const float* Gp = G;
        float* chp = c_hist;
        unsigned* gcp = grp_ctr;
        unsigned* mp = master;
        int t0v = t0, Tcv = Tc, Mv = M;
        void* args[] = {
            (void*)&Gp, (void*)&h0, (void*)&c_init,
            (void*)&w_hi, (void*)&w_ci, (void*)&w_hf, (void*)&w_cf,
            (void*)&w_hc, (void*)&w_ho, (void*)&w_cyo,
            (void*)&out, (void*)&chp, (void*)&gcp, (void*)&mp,
            (void*)&t0v, (void*)&Tcv, (void*)&Mv
        };
        (void)hipLaunchCooperativeKernel((const void*)lstm_scan, dim3(NBLK), dim3(512),
                                         args, SMEM_BYTES, stream);
        c_init = c_hist + (size_t)Tc * HS;
    }
}